// Round 1
// baseline (269.764 us; speedup 1.0000x reference)
//
#include <hip/hip_runtime.h>
#include <hip/hip_bf16.h>
#include <math.h>

#define B_   2
#define N_   2048
#define D_   1024
#define H_   16
#define TD_  3072
#define LOG2E 1.44269504088896340736f
#define SCALE_Q (0.125f * LOG2E)

typedef short  bf16x8 __attribute__((ext_vector_type(8)));
typedef _Float16 f16x8 __attribute__((ext_vector_type(8)));
typedef _Float16 f16x4 __attribute__((ext_vector_type(4)));
typedef float  f32x4  __attribute__((ext_vector_type(4)));
typedef float  f32x16 __attribute__((ext_vector_type(16)));

#define MFMA16(a, b, c)   __builtin_amdgcn_mfma_f32_16x16x32_bf16(a, b, c, 0, 0, 0)
#define MFMA32B(a, b, c)  __builtin_amdgcn_mfma_f32_32x32x16_bf16(a, b, c, 0, 0, 0)
#define MFMA32H(a, b, c)  __builtin_amdgcn_mfma_f32_32x32x16_f16(a, b, c, 0, 0, 0)

__device__ __forceinline__ ushort f2bf(float f) {
    union { float f; unsigned u; } v; v.f = f;
    unsigned r = (v.u + 0x7fffu + ((v.u >> 16) & 1u)) >> 16;
    return (ushort)r;
}
__device__ __forceinline__ unsigned pkrtz(float a, float b) {
    typedef __fp16 h2 __attribute__((ext_vector_type(2)));
    union { h2 h; unsigned u; } c;
    c.h = __builtin_amdgcn_cvt_pkrtz(a, b);
    return c.u;
}
__device__ __forceinline__ void async16(const void* g, void* l) {
    __builtin_amdgcn_global_load_lds(
        (const __attribute__((address_space(1))) unsigned*)g,
        (__attribute__((address_space(3))) unsigned*)l, 16, 0, 0);
}
// v_permlane32_swap_b32: out0 = {a.lanes[0:31], b.lanes[0:31]},
//                        out1 = {a.lanes[32:63], b.lanes[32:63]}
__device__ __forceinline__ void plswap(unsigned &a, unsigned &b) {
    auto r = __builtin_amdgcn_permlane32_swap((int)a, (int)b, false, false);
    a = (unsigned)r[0]; b = (unsigned)r[1];
}

// ---------------------------------------------------------------------------
// Preprocess: bf16 casts, mask->bitmask, log2-domain ppr bias row.
// ---------------------------------------------------------------------------
__global__ __launch_bounds__(256) void preprocess(
    const float* __restrict__ x, const float* __restrict__ W_in,
    const float* __restrict__ W_out, const float* __restrict__ ctx_ppr,
    const float* __restrict__ log_alpha, const int* __restrict__ n_ctx_p,
    const int* __restrict__ mask,
    ushort* __restrict__ xb, ushort* __restrict__ wib, ushort* __restrict__ wob,
    float* __restrict__ biasrow, unsigned* __restrict__ maskbits)
{
    const int J0 = 1048576, J1 = 786432, J2 = 262144, JM = 131072, JB = 2048;
    int t = blockIdx.x * 256 + threadIdx.x;
    if (t < J0 + J1 + J2) {
        const float* src; ushort* dst; int i = t;
        if (i < J0)           { src = x;      dst = xb;  }
        else if (i < J0 + J1) { i -= J0;      src = W_in;  dst = wib; }
        else                  { i -= J0 + J1; src = W_out; dst = wob; }
        float4 v = ((const float4*)src)[i];
        ushort4 o;
        o.x = f2bf(v.x); o.y = f2bf(v.y); o.z = f2bf(v.z); o.w = f2bf(v.w);
        ((ushort4*)dst)[i] = o;
    } else if (t < J0 + J1 + J2 + JM) {
        int i = t - (J0 + J1 + J2);
        const int4* m = (const int4*)(mask + (size_t)i * 32);
        unsigned bits = 0u;
        #pragma unroll
        for (int j = 0; j < 8; ++j) {
            int4 w = m[j];
            bits |= (w.x != 0 ? 1u : 0u) << (j * 4 + 0);
            bits |= (w.y != 0 ? 1u : 0u) << (j * 4 + 1);
            bits |= (w.z != 0 ? 1u : 0u) << (j * 4 + 2);
            bits |= (w.w != 0 ? 1u : 0u) << (j * 4 + 3);
        }
        maskbits[i] = bits;
    } else if (t < J0 + J1 + J2 + JM + JB) {
        int k = t - (J0 + J1 + J2 + JM);
        int nc = n_ctx_p[0];
        float bv = 0.f;
        if (k < nc) bv = log_alpha[0] * __log2f(fmaxf(ctx_ppr[k], 1e-8f));
        biasrow[k] = bv;   // log2-domain bias
    }
}

// ---------------------------------------------------------------------------
// bf16 MFMA NT GEMM, 128xBCOL tile, BK=32, 4 waves.
// MODE 0: f32 out (+bias).  MODE 1: qkv epilogue — q*SCALE_Q->bf16 qk buffer,
// k->bf16 qk buffer, v*trust-gate->f16 V^T buffer [bh*64+dim][2048 tokens].
// ---------------------------------------------------------------------------
template<int BCOL, int MODE>
__global__ __launch_bounds__(256) void gemm_bt(
    const ushort* __restrict__ A, const ushort* __restrict__ Bw,
    const float* __restrict__ bias, float* __restrict__ Cout,
    ushort* __restrict__ qkout, _Float16* __restrict__ vTout,
    int Ncol, int K,
    const float* __restrict__ ctx_trust, const float* __restrict__ trust_scale,
    const int* __restrict__ n_ctx_p)
{
    constexpr int NT = BCOL / 32;      // col 16-tiles per wave
    __shared__ ushort tA[128 * 32];
    __shared__ ushort tB[BCOL * 32];
    const int tid = threadIdx.x;
    const int lane = tid & 63, wv = tid >> 6;
    const int ln = lane & 15, kg = lane >> 4;
    const int rh = wv >> 1, ch = wv & 1;
    const int row0 = blockIdx.y * 128, col0 = blockIdx.x * BCOL;

    int offA[4], offB[NT];
    #pragma unroll
    for (int i = 0; i < 4; ++i) {
        int ra = rh * 64 + i * 16 + ln;
        offA[i] = ra * 32 + ((kg ^ ((ra >> 1) & 3)) << 3);
    }
    #pragma unroll
    for (int i = 0; i < NT; ++i) {
        int rb = ch * (BCOL / 2) + i * 16 + ln;
        offB[i] = rb * 32 + ((kg ^ ((rb >> 1) & 3)) << 3);
    }
    f32x4 acc[4][NT];
    #pragma unroll
    for (int i = 0; i < 4; ++i)
        #pragma unroll
        for (int j = 0; j < NT; ++j) acc[i][j] = (f32x4){0.f, 0.f, 0.f, 0.f};

    for (int kt = 0; kt < K; kt += 32) {
        __syncthreads();
        #pragma unroll
        for (int r2 = 0; r2 < 2; ++r2) {
            int g = r2 * 256 + tid;
            int row = g >> 2;
            int srck = ((g & 3) ^ ((row >> 1) & 3)) << 3;
            async16(A + (size_t)(row0 + row) * K + kt + srck, &tA[g * 8]);
        }
        #pragma unroll
        for (int r2 = 0; r2 < BCOL / 64; ++r2) {
            int g = r2 * 256 + tid;
            int row = g >> 2;
            int srck = ((g & 3) ^ ((row >> 1) & 3)) << 3;
            async16(Bw + (size_t)(col0 + row) * K + kt + srck, &tB[g * 8]);
        }
        __syncthreads();
        bf16x8 af[4], bfr[NT];
        #pragma unroll
        for (int i = 0; i < 4; ++i)  af[i]  = *(const bf16x8*)&tA[offA[i]];
        #pragma unroll
        for (int i = 0; i < NT; ++i) bfr[i] = *(const bf16x8*)&tB[offB[i]];
        #pragma unroll
        for (int mt = 0; mt < 4; ++mt)
            #pragma unroll
            for (int nt = 0; nt < NT; ++nt)
                acc[mt][nt] = MFMA16(af[mt], bfr[nt], acc[mt][nt]);
    }

    const int nctx = n_ctx_p ? n_ctx_p[0] : 0;
    const float ts = trust_scale ? trust_scale[0] : 0.f;
    #pragma unroll
    for (int nt = 0; nt < NT; ++nt) {
        int col = col0 + ch * (BCOL / 2) + nt * 16 + ln;
        float bv = bias[col];
        #pragma unroll
        for (int mt = 0; mt < 4; ++mt) {
            int rbase = row0 + rh * 64 + mt * 16 + kg * 4;
            f32x4 a = acc[mt][nt];
            if (MODE == 0) {
                #pragma unroll
                for (int reg = 0; reg < 4; ++reg)
                    Cout[(size_t)(rbase + reg) * Ncol + col] = a[reg] + bv;
            } else {
                if (col < D_) {
                    #pragma unroll
                    for (int reg = 0; reg < 4; ++reg)
                        qkout[(size_t)(rbase + reg) * 2048 + col] =
                            f2bf((a[reg] + bv) * SCALE_Q);
                } else if (col < 2 * D_) {
                    #pragma unroll
                    for (int reg = 0; reg < 4; ++reg)
                        qkout[(size_t)(rbase + reg) * 2048 + col] = f2bf(a[reg] + bv);
                } else {
                    int vc = col - 2 * D_;
                    int hh = vc >> 6, dim = vc & 63;
                    int bb = rbase >> 11, nbase = rbase & (N_ - 1);
                    ushort4 o;
                    #pragma unroll
                    for (int reg = 0; reg < 4; ++reg) {
                        float v = a[reg] + bv;
                        int n = nbase + reg;
                        if (n < nctx) {
                            float g = 1.f / (1.f + __expf(-ts * ctx_trust[n]));
                            v *= g;
                        }
                        _Float16 hv = (_Float16)v;
                        ((ushort*)&o)[reg] = *(ushort*)&hv;
                    }
                    *(ushort4*)&vTout[((size_t)(bb * 16 + hh) * 64 + dim) * 2048 + nbase] = o;
                }
            }
        }
    }
}

// ---------------------------------------------------------------------------
// Flash attention, 32x32 MFMA, max-less log2-domain softmax.
// Split-K 2-way: blockIdx.z = key half (1024 keys, 16 chunks of 64).
// Block = 4 waves x 32 q = 128 q of one (b,h). K/V async double-buffered via
// global_load_lds, P kept in registers; PV B-frag built with 2x
// v_permlane32_swap_b32 per k-step (no ds_permute, no cndmask chain).
// Each half writes an l-normalized f16 partial + its softmax denominator.
// ---------------------------------------------------------------------------
__global__ __launch_bounds__(256) void attn(
    const ushort* __restrict__ qkb,      // [4096][2048] bf16: q | k
    const _Float16* __restrict__ vT,     // [32*64][2048] f16  (b,h,dim) x token
    const unsigned* __restrict__ maskbits,
    const float* __restrict__ biasrow,   // log2-domain, 0 beyond n_ctx
    const int* __restrict__ n_ctx_p,
    _Float16* __restrict__ op0,          // [4096][1024] f16 partial, key-half 0
    _Float16* __restrict__ op1,          // [4096][1024] f16 partial, key-half 1
    float* __restrict__ lpart)           // [2][32*2048] denominators
{
    __shared__ ushort   Kt[2][64 * 64];
    __shared__ _Float16 Vt[2][64 * 64];
    const int tid = threadIdx.x;
    const int lane = tid & 63, wv = tid >> 6;
    const int q31 = lane & 31, hi = lane >> 5;
    const int b = blockIdx.y >> 4, h = blockIdx.y & 15;
    const int q0w = blockIdx.x * 128 + wv * 32;
    const int kh = blockIdx.z;           // key half: 0 or 1
    const int kbase = kh << 10;
    const int nctx = n_ctx_p[0];

    // Q B-fragments: B[k=dim][n=q], lane n=q31, k = hi*8+j per kstep
    bf16x8 qf[4];
    {
        const ushort* qrow = qkb + (size_t)(b * N_ + q0w + q31) * 2048 + h * 64;
        #pragma unroll
        for (int ks = 0; ks < 4; ++ks)
            qf[ks] = *(const bf16x8*)(qrow + ks * 16 + hi * 8);
    }
    const size_t kgbase = (size_t)(b * N_ + kbase) * 2048 + 1024 + h * 64;
    const _Float16* vbase = vT + (size_t)((b * 16 + h) * 64) * 2048 + kbase;

    f32x16 O[2];
    O[0] = (f32x16)(0.f); O[1] = (f32x16)(0.f);
    float lrun = 0.f;

    // stage chunk 0
    {
        #pragma unroll
        for (int r2 = 0; r2 < 2; ++r2) {
            int g = r2 * 256 + tid; int row = g >> 3; int sg = (g & 7) ^ (row & 7);
            async16(qkb + kgbase + (size_t)row * 2048 + sg * 8, &Kt[0][g * 8]);
        }
        #pragma unroll
        for (int r2 = 0; r2 < 2; ++r2) {
            int g = r2 * 256 + tid; int row = g >> 3; int sg = (g & 7) ^ (row & 7);
            async16(vbase + (size_t)row * 2048 + sg * 8, &Vt[0][g * 8]);
        }
    }

    const int swz = q31 & 7;
    for (int ci = 0; ci < 16; ++ci) {
        const int c0 = ci * 64;
        __syncthreads();   // drains this wave's async issues; all waves aligned
        if (ci < 15) {
            const int c1 = c0 + 64, nb = (ci + 1) & 1;
            #pragma unroll
            for (int r2 = 0; r2 < 2; ++r2) {
                int g = r2 * 256 + tid; int row = g >> 3; int sg = (g & 7) ^ (row & 7);
                async16(qkb + kgbase + (size_t)(c1 + row) * 2048 + sg * 8, &Kt[nb][g * 8]);
            }
            #pragma unroll
            for (int r2 = 0; r2 < 2; ++r2) {
                int g = r2 * 256 + tid; int row = g >> 3; int sg = (g & 7) ^ (row & 7);
                async16(vbase + (size_t)row * 2048 + c1 + sg * 8, &Vt[nb][g * 8]);
            }
        }
        const ushort*   KT = Kt[ci & 1];
        const _Float16* VT = Vt[ci & 1];

        // ---- S^T = K · Q^T  (two 32-key tiles) ----
        f32x16 S[2];
        S[0] = (f32x16)(0.f); S[1] = (f32x16)(0.f);
        #pragma unroll
        for (int t = 0; t < 2; ++t) {
            const int rbase = (t * 32 + q31) * 64;
            #pragma unroll
            for (int ks = 0; ks < 4; ++ks) {
                bf16x8 kf = *(const bf16x8*)&KT[rbase + (((ks * 2 + hi) ^ swz) << 3)];
                S[t] = MFMA32B(kf, qf[ks], S[t]);
            }
        }

        // ---- softmax (no max; fixed -4 offset in log2 domain) ----
        uint2 mw = *(const uint2*)&maskbits[(size_t)(q0w + q31) * 64 + (kbase >> 5) + ci * 2];
        unsigned msh[2] = { mw.x >> (hi * 4), mw.y >> (hi * 4) };
        unsigned pk[2][8];
        float lsum = 0.f;
        const int c0g = kbase + c0;
        const bool has_bias = (c0g < nctx);
        #pragma unroll
        for (int t = 0; t < 2; ++t) {
            float p[16];
            #pragma unroll
            for (int g = 0; g < 4; ++g) {
                f32x4 bb = (f32x4){0.f, 0.f, 0.f, 0.f};
                if (has_bias)
                    bb = *(const f32x4*)&biasrow[c0g + t * 32 + g * 8 + hi * 4];
                #pragma unroll
                for (int r = 0; r < 4; ++r) {
                    const int reg = g * 4 + r;
                    const int br = r + 8 * g;          // bit pos after >> 4*hi
                    float s = S[t][reg] + bb[r] - 4.f;
                    s = ((msh[t] >> br) & 1u) ? -1e30f : s;
                    p[reg] = __builtin_exp2f(s);
                }
            }
            float l0 = (p[0] + p[1]) + (p[2] + p[3]);
            float l1 = (p[4] + p[5]) + (p[6] + p[7]);
            float l2 = (p[8] + p[9]) + (p[10] + p[11]);
            float l3 = (p[12] + p[13]) + (p[14] + p[15]);
            lsum += (l0 + l1) + (l2 + l3);
            #pragma unroll
            for (int i = 0; i < 8; ++i)
                pk[t][i] = pkrtz(p[2 * i], p[2 * i + 1]);
        }
        lrun += lsum;

        // ---- PV: out^T += V^T · P^T ----
        #pragma unroll
        for (int ks = 0; ks < 4; ++ks) {
            const int t = ks >> 1, lo4 = (ks & 1) * 4;
            unsigned w0 = pk[t][lo4 + 0], w1 = pk[t][lo4 + 1];
            unsigned w2 = pk[t][lo4 + 2], w3 = pk[t][lo4 + 3];
            // (frag.u[0],frag.u[2]) = {w0.lo,w2.lo},{w0.hi,w2.hi} = plswap(w0,w2)
            plswap(w0, w2);
            plswap(w1, w3);
            union { f16x8 v; unsigned u[4]; } frag;
            frag.u[0] = w0; frag.u[1] = w1;
            frag.u[2] = w2; frag.u[3] = w3;
            #pragma unroll
            for (int t2 = 0; t2 < 2; ++t2) {
                const int vb = (t2 * 32 + q31) * 64;
                union { f16x8 v; int4 i; } vf;
                vf.i = *(const int4*)&VT[vb + (((ks * 2 + hi) ^ swz) << 3)];
                O[t2] = MFMA32H(vf.v, frag.v, O[t2]);
            }
        }
    }

    // ---- epilogue: normalize this half, store f16 partial + denominator ----
    float l = lrun + __shfl_xor(lrun, 32);
    float inv = 1.f / l;
    _Float16* orow = (kh ? op1 : op0)
                   + (size_t)(b * N_ + q0w + q31) * 1024 + h * 64;
    #pragma unroll
    for (int t = 0; t < 2; ++t)
        #pragma unroll
        for (int g = 0; g < 4; ++g) {
            ushort4 o;
            #pragma unroll
            for (int r = 0; r < 4; ++r) {
                _Float16 hv = (_Float16)(O[t][g * 4 + r] * inv);  // RTN cvt
                ((ushort*)&o)[r] = *(ushort*)&hv;
            }
            *(ushort4*)&orow[t * 32 + g * 8 + hi * 4] = o;
        }
    if (hi == 0)
        lpart[(kh << 16) + (b * 16 + h) * 2048 + q0w + q31] = l;
}

// ---------------------------------------------------------------------------
// Combine the two key-half partials: out = (o0*l0 + o1*l1) / (l0+l1), bf16.
// attb may alias op1: each thread reads exactly the bytes it overwrites.
// ---------------------------------------------------------------------------
__global__ __launch_bounds__(256) void combine(
    const _Float16* __restrict__ op0, const _Float16* __restrict__ op1,
    const float* __restrict__ lpart, ushort* __restrict__ attb)
{
    int t = blockIdx.x * 256 + threadIdx.x;
    size_t idx = (size_t)t * 4;
    int col = (int)(idx & 1023);          // h*64 + d
    int row = (int)(idx >> 10);           // b*2048 + q
    int h = col >> 6;
    int b = row >> 11, q = row & 2047;
    int lidx = (b * 16 + h) * 2048 + q;
    float l0 = lpart[lidx], l1 = lpart[65536 + lidx];
    float inv = 1.f / (l0 + l1);
    float w0 = l0 * inv, w1 = l1 * inv;
    f16x4 a0 = *(const f16x4*)(op0 + idx);
    f16x4 a1 = *(const f16x4*)(op1 + idx);
    ushort4 o;
    #pragma unroll
    for (int r = 0; r < 4; ++r)
        ((ushort*)&o)[r] = f2bf((float)a0[r] * w0 + (float)a1[r] * w1);
    *(ushort4*)(attb + idx) = o;
}

extern "C" void kernel_launch(void* const* d_in, const int* in_sizes, int n_in,
                              void* d_out, int out_size, void* d_ws, size_t ws_size,
                              hipStream_t stream)
{
    const float* x         = (const float*)d_in[0];
    const float* ctx_ppr   = (const float*)d_in[1];
    const float* ctx_trust = (const float*)d_in[2];
    const int*   n_ctx_p   = (const int*)d_in[3];
    const int*   attn_mask = (const int*)d_in[4];
    const float* W_in      = (const float*)d_in[5];
    const float* b_in      = (const float*)d_in[6];
    const float* W_out     = (const float*)d_in[7];
    const float* b_out     = (const float*)d_in[8];
    const float* log_alpha = (const float*)d_in[9];
    const float* trust_sc  = (const float*)d_in[10];
    float* out = (float*)d_out;

    char* ws = (char*)d_ws;
    ushort*    xb       = (ushort*)ws;    ws += (size_t)4096 * 1024 * 2;   // 8 MB
    ushort*    wib      = (ushort*)ws;    ws += (size_t)3072 * 1024 * 2;   // 6 MB
    ushort*    wob      = (ushort*)ws;    ws += (size_t)1024 * 1024 * 2;   // 2 MB
    ushort*    qkb      = (ushort*)ws;    ws += (size_t)4096 * 2048 * 2;   // 16 MB
    _Float16*  vT       = (_Float16*)ws;  ws += (size_t)2048 * 2048 * 2;   // 8 MB
    ushort*    attbuf   = (ushort*)ws;    ws += (size_t)4096 * 1024 * 2;   // 8 MB
    float*     biasrow  = (float*)ws;     ws += 2048 * 4;
    unsigned*  maskbits = (unsigned*)ws;  ws += (size_t)2048 * 64 * 4;     // 512 KB

    // Split-K partials live in workspace that is dead once the QKV GEMM ran:
    //   op0   aliases xb   (8 MB, exact fit)
    //   lpart aliases wib  (512 KB into 6 MB)
    //   op1   aliases attbuf (combine reads op1[i] then writes attb[i]:
    //                         byte-identical per thread, sequential stream)
    _Float16* op0   = (_Float16*)xb;
    _Float16* op1   = (_Float16*)attbuf;
    float*    lpart = (float*)wib;

    hipLaunchKernelGGL(preprocess, dim3(8712), dim3(256), 0, stream,
                       x, W_in, W_out, ctx_ppr, log_alpha, n_ctx_p, attn_mask,
                       xb, wib, wob, biasrow, maskbits);

    hipLaunchKernelGGL((gemm_bt<128, 1>), dim3(24, 32), dim3(256), 0, stream,
                       xb, wib, b_in, (float*)nullptr, qkb, vT, TD_, 1024,
                       ctx_trust, trust_sc, n_ctx_p);

    hipLaunchKernelGGL(attn, dim3(16, 32, 2), dim3(256), 0, stream,
                       qkb, vT, maskbits, biasrow, n_ctx_p, op0, op1, lpart);

    hipLaunchKernelGGL(combine, dim3(4096), dim3(256), 0, stream,
                       op0, op1, lpart, attbuf);

    hipLaunchKernelGGL((gemm_bt<64, 0>), dim3(16, 32), dim3(256), 0, stream,
                       attbuf, wob, b_out, out, (ushort*)nullptr, (_Float16*)nullptr,
                       1024, 1024, ctx_trust, trust_sc, n_ctx_p);
}

// Round 2
// 269.601 us; speedup vs baseline: 1.0006x; 1.0006x over previous
//
#include <hip/hip_runtime.h>
#include <hip/hip_bf16.h>
#include <math.h>

#define B_   2
#define N_   2048
#define D_   1024
#define H_   16
#define TD_  3072
#define LOG2E 1.44269504088896340736f
#define SCALE_Q (0.125f * LOG2E)

typedef short  bf16x8 __attribute__((ext_vector_type(8)));
typedef _Float16 f16x8 __attribute__((ext_vector_type(8)));
typedef _Float16 f16x4 __attribute__((ext_vector_type(4)));
typedef float  f32x4  __attribute__((ext_vector_type(4)));
typedef float  f32x16 __attribute__((ext_vector_type(16)));

#define MFMA16(a, b, c)   __builtin_amdgcn_mfma_f32_16x16x32_bf16(a, b, c, 0, 0, 0)
#define MFMA32B(a, b, c)  __builtin_amdgcn_mfma_f32_32x32x16_bf16(a, b, c, 0, 0, 0)
#define MFMA32H(a, b, c)  __builtin_amdgcn_mfma_f32_32x32x16_f16(a, b, c, 0, 0, 0)

__device__ __forceinline__ ushort f2bf(float f) {
    union { float f; unsigned u; } v; v.f = f;
    unsigned r = (v.u + 0x7fffu + ((v.u >> 16) & 1u)) >> 16;
    return (ushort)r;
}
__device__ __forceinline__ unsigned pkrtz(float a, float b) {
    typedef __fp16 h2 __attribute__((ext_vector_type(2)));
    union { h2 h; unsigned u; } c;
    c.h = __builtin_amdgcn_cvt_pkrtz(a, b);
    return c.u;
}
__device__ __forceinline__ void async16(const void* g, void* l) {
    __builtin_amdgcn_global_load_lds(
        (const __attribute__((address_space(1))) unsigned*)g,
        (__attribute__((address_space(3))) unsigned*)l, 16, 0, 0);
}
// v_permlane32_swap_b32: out0 = {a.lanes[0:31], b.lanes[0:31]},
//                        out1 = {a.lanes[32:63], b.lanes[32:63]}
__device__ __forceinline__ void plswap(unsigned &a, unsigned &b) {
    auto r = __builtin_amdgcn_permlane32_swap((int)a, (int)b, false, false);
    a = (unsigned)r[0]; b = (unsigned)r[1];
}

// ---------------------------------------------------------------------------
// Preprocess: bf16 casts, mask->bitmask, log2-domain ppr bias row.
// ---------------------------------------------------------------------------
__global__ __launch_bounds__(256) void preprocess(
    const float* __restrict__ x, const float* __restrict__ W_in,
    const float* __restrict__ W_out, const float* __restrict__ ctx_ppr,
    const float* __restrict__ log_alpha, const int* __restrict__ n_ctx_p,
    const int* __restrict__ mask,
    ushort* __restrict__ xb, ushort* __restrict__ wib, ushort* __restrict__ wob,
    float* __restrict__ biasrow, unsigned* __restrict__ maskbits)
{
    const int J0 = 1048576, J1 = 786432, J2 = 262144, JM = 131072, JB = 2048;
    int t = blockIdx.x * 256 + threadIdx.x;
    if (t < J0 + J1 + J2) {
        const float* src; ushort* dst; int i = t;
        if (i < J0)           { src = x;      dst = xb;  }
        else if (i < J0 + J1) { i -= J0;      src = W_in;  dst = wib; }
        else                  { i -= J0 + J1; src = W_out; dst = wob; }
        float4 v = ((const float4*)src)[i];
        ushort4 o;
        o.x = f2bf(v.x); o.y = f2bf(v.y); o.z = f2bf(v.z); o.w = f2bf(v.w);
        ((ushort4*)dst)[i] = o;
    } else if (t < J0 + J1 + J2 + JM) {
        int i = t - (J0 + J1 + J2);
        const int4* m = (const int4*)(mask + (size_t)i * 32);
        unsigned bits = 0u;
        #pragma unroll
        for (int j = 0; j < 8; ++j) {
            int4 w = m[j];
            bits |= (w.x != 0 ? 1u : 0u) << (j * 4 + 0);
            bits |= (w.y != 0 ? 1u : 0u) << (j * 4 + 1);
            bits |= (w.z != 0 ? 1u : 0u) << (j * 4 + 2);
            bits |= (w.w != 0 ? 1u : 0u) << (j * 4 + 3);
        }
        maskbits[i] = bits;
    } else if (t < J0 + J1 + J2 + JM + JB) {
        int k = t - (J0 + J1 + J2 + JM);
        int nc = n_ctx_p[0];
        float bv = 0.f;
        if (k < nc) bv = log_alpha[0] * __log2f(fmaxf(ctx_ppr[k], 1e-8f));
        biasrow[k] = bv;   // log2-domain bias
    }
}

// ---------------------------------------------------------------------------
// bf16 MFMA NT GEMM, 128xBCOL tile, BK=32, 4 waves.
// MODE 0: f32 out (+bias).  MODE 1: qkv epilogue — q*SCALE_Q->bf16 qk buffer,
// k->bf16 qk buffer, v*trust-gate->f16 V^T buffer [bh*64+dim][2048 tokens].
// ---------------------------------------------------------------------------
template<int BCOL, int MODE>
__global__ __launch_bounds__(256) void gemm_bt(
    const ushort* __restrict__ A, const ushort* __restrict__ Bw,
    const float* __restrict__ bias, float* __restrict__ Cout,
    ushort* __restrict__ qkout, _Float16* __restrict__ vTout,
    int Ncol, int K,
    const float* __restrict__ ctx_trust, const float* __restrict__ trust_scale,
    const int* __restrict__ n_ctx_p)
{
    constexpr int NT = BCOL / 32;      // col 16-tiles per wave
    __shared__ ushort tA[128 * 32];
    __shared__ ushort tB[BCOL * 32];
    const int tid = threadIdx.x;
    const int lane = tid & 63, wv = tid >> 6;
    const int ln = lane & 15, kg = lane >> 4;
    const int rh = wv >> 1, ch = wv & 1;
    const int row0 = blockIdx.y * 128, col0 = blockIdx.x * BCOL;

    int offA[4], offB[NT];
    #pragma unroll
    for (int i = 0; i < 4; ++i) {
        int ra = rh * 64 + i * 16 + ln;
        offA[i] = ra * 32 + ((kg ^ ((ra >> 1) & 3)) << 3);
    }
    #pragma unroll
    for (int i = 0; i < NT; ++i) {
        int rb = ch * (BCOL / 2) + i * 16 + ln;
        offB[i] = rb * 32 + ((kg ^ ((rb >> 1) & 3)) << 3);
    }
    f32x4 acc[4][NT];
    #pragma unroll
    for (int i = 0; i < 4; ++i)
        #pragma unroll
        for (int j = 0; j < NT; ++j) acc[i][j] = (f32x4){0.f, 0.f, 0.f, 0.f};

    for (int kt = 0; kt < K; kt += 32) {
        __syncthreads();
        #pragma unroll
        for (int r2 = 0; r2 < 2; ++r2) {
            int g = r2 * 256 + tid;
            int row = g >> 2;
            int srck = ((g & 3) ^ ((row >> 1) & 3)) << 3;
            async16(A + (size_t)(row0 + row) * K + kt + srck, &tA[g * 8]);
        }
        #pragma unroll
        for (int r2 = 0; r2 < BCOL / 64; ++r2) {
            int g = r2 * 256 + tid;
            int row = g >> 2;
            int srck = ((g & 3) ^ ((row >> 1) & 3)) << 3;
            async16(Bw + (size_t)(col0 + row) * K + kt + srck, &tB[g * 8]);
        }
        __syncthreads();
        bf16x8 af[4], bfr[NT];
        #pragma unroll
        for (int i = 0; i < 4; ++i)  af[i]  = *(const bf16x8*)&tA[offA[i]];
        #pragma unroll
        for (int i = 0; i < NT; ++i) bfr[i] = *(const bf16x8*)&tB[offB[i]];
        #pragma unroll
        for (int mt = 0; mt < 4; ++mt)
            #pragma unroll
            for (int nt = 0; nt < NT; ++nt)
                acc[mt][nt] = MFMA16(af[mt], bfr[nt], acc[mt][nt]);
    }

    const int nctx = n_ctx_p ? n_ctx_p[0] : 0;
    const float ts = trust_scale ? trust_scale[0] : 0.f;
    #pragma unroll
    for (int nt = 0; nt < NT; ++nt) {
        int col = col0 + ch * (BCOL / 2) + nt * 16 + ln;
        float bv = bias[col];
        #pragma unroll
        for (int mt = 0; mt < 4; ++mt) {
            int rbase = row0 + rh * 64 + mt * 16 + kg * 4;
            f32x4 a = acc[mt][nt];
            if (MODE == 0) {
                #pragma unroll
                for (int reg = 0; reg < 4; ++reg)
                    Cout[(size_t)(rbase + reg) * Ncol + col] = a[reg] + bv;
            } else {
                if (col < D_) {
                    #pragma unroll
                    for (int reg = 0; reg < 4; ++reg)
                        qkout[(size_t)(rbase + reg) * 2048 + col] =
                            f2bf((a[reg] + bv) * SCALE_Q);
                } else if (col < 2 * D_) {
                    #pragma unroll
                    for (int reg = 0; reg < 4; ++reg)
                        qkout[(size_t)(rbase + reg) * 2048 + col] = f2bf(a[reg] + bv);
                } else {
                    int vc = col - 2 * D_;
                    int hh = vc >> 6, dim = vc & 63;
                    int bb = rbase >> 11, nbase = rbase & (N_ - 1);
                    ushort4 o;
                    #pragma unroll
                    for (int reg = 0; reg < 4; ++reg) {
                        float v = a[reg] + bv;
                        int n = nbase + reg;
                        if (n < nctx) {
                            float g = 1.f / (1.f + __expf(-ts * ctx_trust[n]));
                            v *= g;
                        }
                        _Float16 hv = (_Float16)v;
                        ((ushort*)&o)[reg] = *(ushort*)&hv;
                    }
                    *(ushort4*)&vTout[((size_t)(bb * 16 + hh) * 64 + dim) * 2048 + nbase] = o;
                }
            }
        }
    }
}

// ---------------------------------------------------------------------------
// Flash attention, 32x32 MFMA, max-less log2-domain softmax.
// Split-K 2-way (blockIdx.z = key half, 16 chunks of 64 keys each).
// Counted-vmcnt pipeline: K triple-buffered (prefetch distance 2), V
// double-buffered (distance 1); raw s_barrier pairs; steady-state
// s_waitcnt vmcnt(7) — never a full drain in the main loop. Mask words
// prefetched one chunk ahead so their VMEM slot stays oldest-first.
// Per-tile S/softmax/PV sequencing keeps unified VGPR+AGPR <= 128 so
// __launch_bounds__(256,4) gives 4 blocks/CU (LDS 40 KB = exactly 4).
// ---------------------------------------------------------------------------
__global__ __launch_bounds__(256, 4) void attn(
    const ushort* __restrict__ qkb,      // [4096][2048] bf16: q | k
    const _Float16* __restrict__ vT,     // [32*64][2048] f16  (b,h,dim) x token
    const unsigned* __restrict__ maskbits,
    const float* __restrict__ biasrow,   // log2-domain, 0 beyond n_ctx
    const int* __restrict__ n_ctx_p,
    _Float16* __restrict__ op0,          // [4096][1024] f16 partial, key-half 0
    _Float16* __restrict__ op1,          // [4096][1024] f16 partial, key-half 1
    float* __restrict__ lpart)           // [2][32*2048] denominators
{
    __shared__ ushort   Kt[3][64 * 64];  // 24 KB
    __shared__ _Float16 Vt[2][64 * 64];  // 16 KB
    const int tid = threadIdx.x;
    const int lane = tid & 63, wv = tid >> 6;
    const int q31 = lane & 31, hi = lane >> 5;
    const int b = blockIdx.y >> 4, h = blockIdx.y & 15;
    const int q0w = blockIdx.x * 128 + wv * 32;
    const int kh = blockIdx.z;           // key half: 0 or 1
    const int kbase = kh << 10;
    const int nctx = n_ctx_p[0];

    // Q B-fragments: B[k=dim][n=q], lane n=q31, k = hi*8+j per kstep
    bf16x8 qf[4];
    {
        const ushort* qrow = qkb + (size_t)(b * N_ + q0w + q31) * 2048 + h * 64;
        #pragma unroll
        for (int ks = 0; ks < 4; ++ks)
            qf[ks] = *(const bf16x8*)(qrow + ks * 16 + hi * 8);
    }
    const size_t kgbase = (size_t)(b * N_ + kbase) * 2048 + 1024 + h * 64;
    const _Float16* vbase = vT + (size_t)((b * 16 + h) * 64) * 2048 + kbase;
    const unsigned* mrow = maskbits + (size_t)(q0w + q31) * 64 + (kbase >> 5);

    // per-thread staging offsets within one 64x64 chunk (2B elements):
    // slot r2: g = r2*256+tid, row = g>>3, col-group sg = (g&7)^(row&7)
    int goff[2], ldso[2];
    #pragma unroll
    for (int r2 = 0; r2 < 2; ++r2) {
        int g = r2 * 256 + tid, row = g >> 3, sg = (g & 7) ^ (row & 7);
        goff[r2] = row * 2048 + sg * 8;
        ldso[r2] = g * 8;
    }

    f32x16 O[2];
    O[0] = (f32x16)(0.f); O[1] = (f32x16)(0.f);
    float lrun = 0.f;

    // ---- prologue: FIFO = [mask0][K0 x2][V0 x2][K1 x2] ----
    uint2 mcur = *(const uint2*)&mrow[0];
    asm volatile("" ::: "memory");       // pin mask load before the asyncs
    {
        const ushort* gp0 = qkb + kgbase;
        #pragma unroll
        for (int r2 = 0; r2 < 2; ++r2) async16(gp0 + goff[r2], &Kt[0][ldso[r2]]);
        const _Float16* vp = vbase;
        #pragma unroll
        for (int r2 = 0; r2 < 2; ++r2) async16(vp + goff[r2], &Vt[0][ldso[r2]]);
        const ushort* gp1 = qkb + kgbase + (size_t)(64 * 2048);
        #pragma unroll
        for (int r2 = 0; r2 < 2; ++r2) async16(gp1 + goff[r2], &Kt[1][ldso[r2]]);
    }

    const int swz = q31 & 7;
    int kb = 0;                           // Kt buffer holding chunk ci
    #pragma unroll 1
    for (int ci = 0; ci < 16; ++ci) {
        // bar1: all waves done computing chunk ci-1 -> buffers reusable
        asm volatile("s_barrier" ::: "memory");
        uint2 mnext = mcur;
        if (ci < 15) {
            mnext = *(const uint2*)&mrow[(ci + 1) * 2];
            asm volatile("" ::: "memory");   // pin mask before V asyncs
            const _Float16* vp = vbase + (ci + 1) * 64;
            #pragma unroll
            for (int r2 = 0; r2 < 2; ++r2)
                async16(vp + goff[r2], &Vt[(ci + 1) & 1][ldso[r2]]);
        }
        if (ci < 14) {
            int nb = kb + 2; if (nb >= 3) nb -= 3;
            const ushort* gp = qkb + kgbase + (size_t)(ci + 2) * (64 * 2048);
            #pragma unroll
            for (int r2 = 0; r2 < 2; ++r2)
                async16(gp + goff[r2], &Kt[nb][ldso[r2]]);
        }
        // counted wait: retire through V(ci)+mask(ci); keep newer prefetches
        // in flight. Steady: [Kci+1 x2][maskci+1][Vci+1 x2][Kci+2 x2] = 7.
        if (ci < 14)       asm volatile("s_waitcnt vmcnt(7)" ::: "memory");
        else if (ci == 14) asm volatile("s_waitcnt vmcnt(5)" ::: "memory");
        else               asm volatile("s_waitcnt vmcnt(0)" ::: "memory");
        // bar2: all waves' chunk-ci loads have landed
        asm volatile("s_barrier" ::: "memory");

        const ushort*   KT = Kt[kb];
        const _Float16* VT = Vt[ci & 1];
        const int c0g = kbase + ci * 64;
        const bool has_bias = (c0g < nctx);
        unsigned msh[2] = { mcur.x >> (hi * 4), mcur.y >> (hi * 4) };
        float lsum = 0.f;

        #pragma unroll
        for (int t = 0; t < 2; ++t) {
            // ---- S^T tile = K . Q^T ----
            f32x16 S = (f32x16)(0.f);
            const int rbase = (t * 32 + q31) * 64;
            #pragma unroll
            for (int ks = 0; ks < 4; ++ks) {
                bf16x8 kf = *(const bf16x8*)&KT[rbase + (((ks * 2 + hi) ^ swz) << 3)];
                S = MFMA32B(kf, qf[ks], S);
            }
            // ---- softmax (no max; fixed -4 offset in log2 domain) ----
            float p[16];
            #pragma unroll
            for (int g = 0; g < 4; ++g) {
                f32x4 bb;
                if (has_bias)
                    bb = *(const f32x4*)&biasrow[c0g + t * 32 + g * 8 + hi * 4];
                #pragma unroll
                for (int r = 0; r < 4; ++r) {
                    const int reg = g * 4 + r;
                    const int br = r + 8 * g;      // bit pos after >> 4*hi
                    float s = S[reg] - 4.f;
                    if (has_bias) s += bb[r];
                    s = ((msh[t] >> br) & 1u) ? -1e30f : s;
                    p[reg] = __builtin_exp2f(s);
                }
            }
            float l0 = (p[0] + p[1]) + (p[2] + p[3]);
            float l1 = (p[4] + p[5]) + (p[6] + p[7]);
            float l2 = (p[8] + p[9]) + (p[10] + p[11]);
            float l3 = (p[12] + p[13]) + (p[14] + p[15]);
            lsum += (l0 + l1) + (l2 + l3);
            unsigned pk[8];
            #pragma unroll
            for (int i = 0; i < 8; ++i)
                pk[i] = pkrtz(p[2 * i], p[2 * i + 1]);

            // ---- PV for this tile: out^T += V^T . P^T (k-slots 2t, 2t+1) ----
            #pragma unroll
            for (int kss = 0; kss < 2; ++kss) {
                const int ks = 2 * t + kss, lo4 = kss * 4;
                unsigned w0 = pk[lo4 + 0], w1 = pk[lo4 + 1];
                unsigned w2 = pk[lo4 + 2], w3 = pk[lo4 + 3];
                plswap(w0, w2);
                plswap(w1, w3);
                union { f16x8 v; unsigned u[4]; } frag;
                frag.u[0] = w0; frag.u[1] = w1;
                frag.u[2] = w2; frag.u[3] = w3;
                #pragma unroll
                for (int t2 = 0; t2 < 2; ++t2) {
                    const int vb = (t2 * 32 + q31) * 64;
                    union { f16x8 v; int4 i4; } vf;
                    vf.i4 = *(const int4*)&VT[vb + (((ks * 2 + hi) ^ swz) << 3)];
                    O[t2] = MFMA32H(vf.v, frag.v, O[t2]);
                }
            }
        }
        lrun += lsum;
        mcur = mnext;
        kb = kb + 1; if (kb >= 3) kb -= 3;
    }

    // ---- epilogue: normalize this half, store f16 partial + denominator ----
    float l = lrun + __shfl_xor(lrun, 32);
    float inv = 1.f / l;
    _Float16* orow = (kh ? op1 : op0)
                   + (size_t)(b * N_ + q0w + q31) * 1024 + h * 64;
    #pragma unroll
    for (int t = 0; t < 2; ++t)
        #pragma unroll
        for (int g = 0; g < 4; ++g) {
            ushort4 o;
            #pragma unroll
            for (int r = 0; r < 4; ++r) {
                _Float16 hv = (_Float16)(O[t][g * 4 + r] * inv);  // RTN cvt
                ((ushort*)&o)[r] = *(ushort*)&hv;
            }
            *(ushort4*)&orow[t * 32 + g * 8 + hi * 4] = o;
        }
    if (hi == 0)
        lpart[(kh << 16) + (b * 16 + h) * 2048 + q0w + q31] = l;
}

// ---------------------------------------------------------------------------
// Combine the two key-half partials: out = (o0*l0 + o1*l1) / (l0+l1), bf16.
// attb may alias op1: each thread reads exactly the bytes it overwrites.
// ---------------------------------------------------------------------------
__global__ __launch_bounds__(256) void combine(
    const _Float16* __restrict__ op0, const _Float16* __restrict__ op1,
    const float* __restrict__ lpart, ushort* __restrict__ attb)
{
    int t = blockIdx.x * 256 + threadIdx.x;
    size_t idx = (size_t)t * 4;
    int col = (int)(idx & 1023);          // h*64 + d
    int row = (int)(idx >> 10);           // b*2048 + q
    int h = col >> 6;
    int b = row >> 11, q = row & 2047;
    int lidx = (b * 16 + h) * 2048 + q;
    float l0 = lpart[lidx], l1 = lpart[65536 + lidx];
    float inv = 1.f / (l0 + l1);
    float w0 = l0 * inv, w1 = l1 * inv;
    f16x4 a0 = *(const f16x4*)(op0 + idx);
    f16x4 a1 = *(const f16x4*)(op1 + idx);
    ushort4 o;
    #pragma unroll
    for (int r = 0; r < 4; ++r)
        ((ushort*)&o)[r] = f2bf((float)a0[r] * w0 + (float)a1[r] * w1);
    *(ushort4*)(attb + idx) = o;
}

extern "C" void kernel_launch(void* const* d_in, const int* in_sizes, int n_in,
                              void* d_out, int out_size, void* d_ws, size_t ws_size,
                              hipStream_t stream)
{
    const float* x         = (const float*)d_in[0];
    const float* ctx_ppr   = (const float*)d_in[1];
    const float* ctx_trust = (const float*)d_in[2];
    const int*   n_ctx_p   = (const int*)d_in[3];
    const int*   attn_mask = (const int*)d_in[4];
    const float* W_in      = (const float*)d_in[5];
    const float* b_in      = (const float*)d_in[6];
    const float* W_out     = (const float*)d_in[7];
    const float* b_out     = (const float*)d_in[8];
    const float* log_alpha = (const float*)d_in[9];
    const float* trust_sc  = (const float*)d_in[10];
    float* out = (float*)d_out;

    char* ws = (char*)d_ws;
    ushort*    xb       = (ushort*)ws;    ws += (size_t)4096 * 1024 * 2;   // 8 MB
    ushort*    wib      = (ushort*)ws;    ws += (size_t)3072 * 1024 * 2;   // 6 MB
    ushort*    wob      = (ushort*)ws;    ws += (size_t)1024 * 1024 * 2;   // 2 MB
    ushort*    qkb      = (ushort*)ws;    ws += (size_t)4096 * 2048 * 2;   // 16 MB
    _Float16*  vT       = (_Float16*)ws;  ws += (size_t)2048 * 2048 * 2;   // 8 MB
    ushort*    attbuf   = (ushort*)ws;    ws += (size_t)4096 * 1024 * 2;   // 8 MB
    float*     biasrow  = (float*)ws;     ws += 2048 * 4;
    unsigned*  maskbits = (unsigned*)ws;  ws += (size_t)2048 * 64 * 4;     // 512 KB

    // Split-K partials live in workspace that is dead once the QKV GEMM ran:
    //   op0   aliases xb   (8 MB, exact fit)
    //   lpart aliases wib  (512 KB into 6 MB)
    //   op1   aliases attbuf (combine reads op1[i] then writes attb[i]:
    //                         byte-identical per thread, sequential stream)
    _Float16* op0   = (_Float16*)xb;
    _Float16* op1   = (_Float16*)attbuf;
    float*    lpart = (float*)wib;

    hipLaunchKernelGGL(preprocess, dim3(8712), dim3(256), 0, stream,
                       x, W_in, W_out, ctx_ppr, log_alpha, n_ctx_p, attn_mask,
                       xb, wib, wob, biasrow, maskbits);

    hipLaunchKernelGGL((gemm_bt<128, 1>), dim3(24, 32), dim3(256), 0, stream,
                       xb, wib, b_in, (float*)nullptr, qkb, vT, TD_, 1024,
                       ctx_trust, trust_sc, n_ctx_p);

    hipLaunchKernelGGL(attn, dim3(16, 32, 2), dim3(256), 0, stream,
                       qkb, vT, maskbits, biasrow, n_ctx_p, op0, op1, lpart);

    hipLaunchKernelGGL(combine, dim3(4096), dim3(256), 0, stream,
                       op0, op1, lpart, attbuf);

    hipLaunchKernelGGL((gemm_bt<64, 0>), dim3(16, 32), dim3(256), 0, stream,
                       attbuf, wob, b_out, out, (ushort*)nullptr, (_Float16*)nullptr,
                       1024, 1024, ctx_trust, trust_sc, n_ctx_p);
}

// Round 3
// 248.000 us; speedup vs baseline: 1.0878x; 1.0871x over previous
//
#include <hip/hip_runtime.h>
#include <hip/hip_bf16.h>
#include <math.h>

#define B_   2
#define N_   2048
#define D_   1024
#define H_   16
#define TD_  3072
#define LOG2E 1.44269504088896340736f
#define SCALE_Q (0.125f * LOG2E)

typedef short  bf16x8 __attribute__((ext_vector_type(8)));
typedef _Float16 f16x8 __attribute__((ext_vector_type(8)));
typedef _Float16 f16x4 __attribute__((ext_vector_type(4)));
typedef float  f32x4  __attribute__((ext_vector_type(4)));
typedef float  f32x16 __attribute__((ext_vector_type(16)));

#define MFMA16(a, b, c)   __builtin_amdgcn_mfma_f32_16x16x32_bf16(a, b, c, 0, 0, 0)
#define MFMA32B(a, b, c)  __builtin_amdgcn_mfma_f32_32x32x16_bf16(a, b, c, 0, 0, 0)
#define MFMA32H(a, b, c)  __builtin_amdgcn_mfma_f32_32x32x16_f16(a, b, c, 0, 0, 0)

__device__ __forceinline__ ushort f2bf(float f) {
    union { float f; unsigned u; } v; v.f = f;
    unsigned r = (v.u + 0x7fffu + ((v.u >> 16) & 1u)) >> 16;
    return (ushort)r;
}
__device__ __forceinline__ unsigned pkrtz(float a, float b) {
    typedef __fp16 h2 __attribute__((ext_vector_type(2)));
    union { h2 h; unsigned u; } c;
    c.h = __builtin_amdgcn_cvt_pkrtz(a, b);
    return c.u;
}
__device__ __forceinline__ void async16(const void* g, void* l) {
    __builtin_amdgcn_global_load_lds(
        (const __attribute__((address_space(1))) unsigned*)g,
        (__attribute__((address_space(3))) unsigned*)l, 16, 0, 0);
}
// v_permlane32_swap_b32: out0 = {a.lanes[0:31], b.lanes[0:31]},
//                        out1 = {a.lanes[32:63], b.lanes[32:63]}
__device__ __forceinline__ void plswap(unsigned &a, unsigned &b) {
    auto r = __builtin_amdgcn_permlane32_swap((int)a, (int)b, false, false);
    a = (unsigned)r[0]; b = (unsigned)r[1];
}

// ---------------------------------------------------------------------------
// Preprocess: bf16 casts, mask->bitmask, log2-domain ppr bias row.
// ---------------------------------------------------------------------------
__global__ __launch_bounds__(256) void preprocess(
    const float* __restrict__ x, const float* __restrict__ W_in,
    const float* __restrict__ W_out, const float* __restrict__ ctx_ppr,
    const float* __restrict__ log_alpha, const int* __restrict__ n_ctx_p,
    const int* __restrict__ mask,
    ushort* __restrict__ xb, ushort* __restrict__ wib, ushort* __restrict__ wob,
    float* __restrict__ biasrow, unsigned* __restrict__ maskbits)
{
    const int J0 = 1048576, J1 = 786432, J2 = 262144, JM = 131072, JB = 2048;
    int t = blockIdx.x * 256 + threadIdx.x;
    if (t < J0 + J1 + J2) {
        const float* src; ushort* dst; int i = t;
        if (i < J0)           { src = x;      dst = xb;  }
        else if (i < J0 + J1) { i -= J0;      src = W_in;  dst = wib; }
        else                  { i -= J0 + J1; src = W_out; dst = wob; }
        float4 v = ((const float4*)src)[i];
        ushort4 o;
        o.x = f2bf(v.x); o.y = f2bf(v.y); o.z = f2bf(v.z); o.w = f2bf(v.w);
        ((ushort4*)dst)[i] = o;
    } else if (t < J0 + J1 + J2 + JM) {
        int i = t - (J0 + J1 + J2);
        const int4* m = (const int4*)(mask + (size_t)i * 32);
        unsigned bits = 0u;
        #pragma unroll
        for (int j = 0; j < 8; ++j) {
            int4 w = m[j];
            bits |= (w.x != 0 ? 1u : 0u) << (j * 4 + 0);
            bits |= (w.y != 0 ? 1u : 0u) << (j * 4 + 1);
            bits |= (w.z != 0 ? 1u : 0u) << (j * 4 + 2);
            bits |= (w.w != 0 ? 1u : 0u) << (j * 4 + 3);
        }
        maskbits[i] = bits;
    } else if (t < J0 + J1 + J2 + JM + JB) {
        int k = t - (J0 + J1 + J2 + JM);
        int nc = n_ctx_p[0];
        float bv = 0.f;
        if (k < nc) bv = log_alpha[0] * __log2f(fmaxf(ctx_ppr[k], 1e-8f));
        biasrow[k] = bv;   // log2-domain bias
    }
}

// ---------------------------------------------------------------------------
// bf16 MFMA NT GEMM, 128xBCOL tile, BK=32, 4 waves.
// MODE 0: f32 out (+bias).  MODE 1: qkv epilogue — q*SCALE_Q->bf16 qk buffer,
// k->bf16 qk buffer, v*trust-gate->f16 V^T buffer [bh*64+dim][2048 tokens].
// ---------------------------------------------------------------------------
template<int BCOL, int MODE>
__global__ __launch_bounds__(256) void gemm_bt(
    const ushort* __restrict__ A, const ushort* __restrict__ Bw,
    const float* __restrict__ bias, float* __restrict__ Cout,
    ushort* __restrict__ qkout, _Float16* __restrict__ vTout,
    int Ncol, int K,
    const float* __restrict__ ctx_trust, const float* __restrict__ trust_scale,
    const int* __restrict__ n_ctx_p)
{
    constexpr int NT = BCOL / 32;      // col 16-tiles per wave
    __shared__ ushort tA[128 * 32];
    __shared__ ushort tB[BCOL * 32];
    const int tid = threadIdx.x;
    const int lane = tid & 63, wv = tid >> 6;
    const int ln = lane & 15, kg = lane >> 4;
    const int rh = wv >> 1, ch = wv & 1;
    const int row0 = blockIdx.y * 128, col0 = blockIdx.x * BCOL;

    int offA[4], offB[NT];
    #pragma unroll
    for (int i = 0; i < 4; ++i) {
        int ra = rh * 64 + i * 16 + ln;
        offA[i] = ra * 32 + ((kg ^ ((ra >> 1) & 3)) << 3);
    }
    #pragma unroll
    for (int i = 0; i < NT; ++i) {
        int rb = ch * (BCOL / 2) + i * 16 + ln;
        offB[i] = rb * 32 + ((kg ^ ((rb >> 1) & 3)) << 3);
    }
    f32x4 acc[4][NT];
    #pragma unroll
    for (int i = 0; i < 4; ++i)
        #pragma unroll
        for (int j = 0; j < NT; ++j) acc[i][j] = (f32x4){0.f, 0.f, 0.f, 0.f};

    for (int kt = 0; kt < K; kt += 32) {
        __syncthreads();
        #pragma unroll
        for (int r2 = 0; r2 < 2; ++r2) {
            int g = r2 * 256 + tid;
            int row = g >> 2;
            int srck = ((g & 3) ^ ((row >> 1) & 3)) << 3;
            async16(A + (size_t)(row0 + row) * K + kt + srck, &tA[g * 8]);
        }
        #pragma unroll
        for (int r2 = 0; r2 < BCOL / 64; ++r2) {
            int g = r2 * 256 + tid;
            int row = g >> 2;
            int srck = ((g & 3) ^ ((row >> 1) & 3)) << 3;
            async16(Bw + (size_t)(col0 + row) * K + kt + srck, &tB[g * 8]);
        }
        __syncthreads();
        bf16x8 af[4], bfr[NT];
        #pragma unroll
        for (int i = 0; i < 4; ++i)  af[i]  = *(const bf16x8*)&tA[offA[i]];
        #pragma unroll
        for (int i = 0; i < NT; ++i) bfr[i] = *(const bf16x8*)&tB[offB[i]];
        #pragma unroll
        for (int mt = 0; mt < 4; ++mt)
            #pragma unroll
            for (int nt = 0; nt < NT; ++nt)
                acc[mt][nt] = MFMA16(af[mt], bfr[nt], acc[mt][nt]);
    }

    const int nctx = n_ctx_p ? n_ctx_p[0] : 0;
    const float ts = trust_scale ? trust_scale[0] : 0.f;
    #pragma unroll
    for (int nt = 0; nt < NT; ++nt) {
        int col = col0 + ch * (BCOL / 2) + nt * 16 + ln;
        float bv = bias[col];
        #pragma unroll
        for (int mt = 0; mt < 4; ++mt) {
            int rbase = row0 + rh * 64 + mt * 16 + kg * 4;
            f32x4 a = acc[mt][nt];
            if (MODE == 0) {
                #pragma unroll
                for (int reg = 0; reg < 4; ++reg)
                    Cout[(size_t)(rbase + reg) * Ncol + col] = a[reg] + bv;
            } else {
                if (col < D_) {
                    #pragma unroll
                    for (int reg = 0; reg < 4; ++reg)
                        qkout[(size_t)(rbase + reg) * 2048 + col] =
                            f2bf((a[reg] + bv) * SCALE_Q);
                } else if (col < 2 * D_) {
                    #pragma unroll
                    for (int reg = 0; reg < 4; ++reg)
                        qkout[(size_t)(rbase + reg) * 2048 + col] = f2bf(a[reg] + bv);
                } else {
                    int vc = col - 2 * D_;
                    int hh = vc >> 6, dim = vc & 63;
                    int bb = rbase >> 11, nbase = rbase & (N_ - 1);
                    ushort4 o;
                    #pragma unroll
                    for (int reg = 0; reg < 4; ++reg) {
                        float v = a[reg] + bv;
                        int n = nbase + reg;
                        if (n < nctx) {
                            float g = 1.f / (1.f + __expf(-ts * ctx_trust[n]));
                            v *= g;
                        }
                        _Float16 hv = (_Float16)v;
                        ((ushort*)&o)[reg] = *(ushort*)&hv;
                    }
                    *(ushort4*)&vTout[((size_t)(bb * 16 + hh) * 64 + dim) * 2048 + nbase] = o;
                }
            }
        }
    }
}

// ---------------------------------------------------------------------------
// Flash attention, 32x32 MFMA, max-less log2-domain softmax.
// Split-K 2-way (blockIdx.z = key half, 16 chunks of 64 keys each).
// Counted-vmcnt pipeline: K triple-buffered (distance 2), V double-buffered
// (distance 1); raw s_barrier pairs; steady-state s_waitcnt vmcnt(7).
// VALU diet: bfe/bfi mask select, no -4 offset (constant factor cancels in
// O/l), raw v_exp_f32, p->pkrtz fused per quad. Chunk order rotated per
// block (softmax sum is commutative) so co-resident blocks de-convoy their
// VALU/MFMA phases; s_setprio(1) around MFMA clusters.
// ---------------------------------------------------------------------------
__global__ __launch_bounds__(256, 4) void attn(
    const ushort* __restrict__ qkb,      // [4096][2048] bf16: q | k
    const _Float16* __restrict__ vT,     // [32*64][2048] f16  (b,h,dim) x token
    const unsigned* __restrict__ maskbits,
    const float* __restrict__ biasrow,   // log2-domain, 0 beyond n_ctx
    const int* __restrict__ n_ctx_p,
    _Float16* __restrict__ op0,          // [4096][1024] f16 partial, key-half 0
    _Float16* __restrict__ op1,          // [4096][1024] f16 partial, key-half 1
    float* __restrict__ lpart)           // [2][32*2048] denominators
{
    __shared__ ushort   Kt[3][64 * 64];  // 24 KB
    __shared__ _Float16 Vt[2][64 * 64];  // 16 KB
    const int tid = threadIdx.x;
    const int lane = tid & 63, wv = tid >> 6;
    const int q31 = lane & 31, hi = lane >> 5;
    const int b = blockIdx.y >> 4, h = blockIdx.y & 15;
    const int q0w = blockIdx.x * 128 + wv * 32;
    const int kh = blockIdx.z;           // key half: 0 or 1
    const int kbase = kh << 10;
    const int nctx = n_ctx_p[0];

    // chunk-order rotation: co-resident blocks are ~256 apart in linear id
    const int lin = blockIdx.x + (blockIdx.y << 4) + (blockIdx.z << 9);
    const int rot = ((lin >> 8) << 2) & 15;

    union fi { float f; int i; };
    fi ng; ng.f = -1e30f;
    const int NEGI = ng.i;

    // Q B-fragments: B[k=dim][n=q], lane n=q31, k = hi*8+j per kstep
    bf16x8 qf[4];
    {
        const ushort* qrow = qkb + (size_t)(b * N_ + q0w + q31) * 2048 + h * 64;
        #pragma unroll
        for (int ks = 0; ks < 4; ++ks)
            qf[ks] = *(const bf16x8*)(qrow + ks * 16 + hi * 8);
    }
    const size_t kgbase = (size_t)(b * N_ + kbase) * 2048 + 1024 + h * 64;
    const _Float16* vbase = vT + (size_t)((b * 16 + h) * 64) * 2048 + kbase;
    const unsigned* mrow = maskbits + (size_t)(q0w + q31) * 64 + (kbase >> 5);

    // per-thread staging offsets within one 64x64 chunk (2B elements):
    // slot r2: g = r2*256+tid, row = g>>3, col-group sg = (g&7)^(row&7)
    int goff[2], ldso[2];
    #pragma unroll
    for (int r2 = 0; r2 < 2; ++r2) {
        int g = r2 * 256 + tid, row = g >> 3, sg = (g & 7) ^ (row & 7);
        goff[r2] = row * 2048 + sg * 8;
        ldso[r2] = g * 8;
    }

    f32x16 O[2];
    O[0] = (f32x16)(0.f); O[1] = (f32x16)(0.f);
    float lrun = 0.f;

    // ---- prologue: FIFO = [mask0][K0 x2][V0 x2][K1 x2] (rotated chunks) ----
    const int cp0 = rot, cp1 = (rot + 1) & 15;
    uint2 mcur = *(const uint2*)&mrow[cp0 * 2];
    asm volatile("" ::: "memory");       // pin mask load before the asyncs
    {
        const ushort* gp0 = qkb + kgbase + (size_t)cp0 * (64 * 2048);
        #pragma unroll
        for (int r2 = 0; r2 < 2; ++r2) async16(gp0 + goff[r2], &Kt[0][ldso[r2]]);
        const _Float16* vp = vbase + cp0 * 64;
        #pragma unroll
        for (int r2 = 0; r2 < 2; ++r2) async16(vp + goff[r2], &Vt[0][ldso[r2]]);
        const ushort* gp1 = qkb + kgbase + (size_t)cp1 * (64 * 2048);
        #pragma unroll
        for (int r2 = 0; r2 < 2; ++r2) async16(gp1 + goff[r2], &Kt[1][ldso[r2]]);
    }

    const int swz = q31 & 7;
    int kb = 0;                           // Kt buffer holding chunk ci
    #pragma unroll 1
    for (int ci = 0; ci < 16; ++ci) {
        // bar1: all waves done computing chunk ci-1 -> buffers reusable
        asm volatile("s_barrier" ::: "memory");
        uint2 mnext = mcur;
        if (ci < 15) {
            const int cpv = (ci + 1 + rot) & 15;
            mnext = *(const uint2*)&mrow[cpv * 2];
            asm volatile("" ::: "memory");   // pin mask before V asyncs
            const _Float16* vp = vbase + cpv * 64;
            #pragma unroll
            for (int r2 = 0; r2 < 2; ++r2)
                async16(vp + goff[r2], &Vt[(ci + 1) & 1][ldso[r2]]);
        }
        if (ci < 14) {
            int nb = kb + 2; if (nb >= 3) nb -= 3;
            const int cpk = (ci + 2 + rot) & 15;
            const ushort* gp = qkb + kgbase + (size_t)cpk * (64 * 2048);
            #pragma unroll
            for (int r2 = 0; r2 < 2; ++r2)
                async16(gp + goff[r2], &Kt[nb][ldso[r2]]);
        }
        // counted wait: retire through V(ci)+mask(ci); keep newer prefetches
        // in flight. Steady: [Kci+1 x2][maskci+1][Vci+1 x2][Kci+2 x2] = 7.
        if (ci < 14)       asm volatile("s_waitcnt vmcnt(7)" ::: "memory");
        else if (ci == 14) asm volatile("s_waitcnt vmcnt(5)" ::: "memory");
        else               asm volatile("s_waitcnt vmcnt(0)" ::: "memory");
        // bar2: all waves' chunk-ci loads have landed
        asm volatile("s_barrier" ::: "memory");

        const ushort*   KT = Kt[kb];
        const _Float16* VT = Vt[ci & 1];
        const int cp = (ci + rot) & 15;
        const int c0g = kbase + cp * 64;
        const bool has_bias = (c0g < nctx);
        float lsum = 0.f;

        #pragma unroll
        for (int t = 0; t < 2; ++t) {
            // ---- S^T tile = K . Q^T ----
            f32x16 S = (f32x16)(0.f);
            const int rbase = (t * 32 + q31) * 64;
            __builtin_amdgcn_s_setprio(1);
            #pragma unroll
            for (int ks = 0; ks < 4; ++ks) {
                bf16x8 kf = *(const bf16x8*)&KT[rbase + (((ks * 2 + hi) ^ swz) << 3)];
                S = MFMA32B(kf, qf[ks], S);
            }
            __builtin_amdgcn_s_setprio(0);

            // ---- softmax (no max, no offset; mask via bfe+bfi) ----
            const unsigned msh = (t ? mcur.y : mcur.x) >> (hi * 4);
            unsigned pk[8];
            float lt = 0.f;
            #pragma unroll
            for (int g = 0; g < 4; ++g) {
                f32x4 bb;
                if (has_bias)
                    bb = *(const f32x4*)&biasrow[c0g + t * 32 + g * 8 + hi * 4];
                float pr[4];
                #pragma unroll
                for (int r = 0; r < 4; ++r) {
                    const int br = r + 8 * g;      // bit pos after >> 4*hi
                    float s = S[g * 4 + r];
                    if (has_bias) s += bb[r];
                    int mi = ((int)(msh << (31 - br))) >> 31;  // v_bfe_i32
                    fi su; su.f = s;
                    su.i = (mi & NEGI) | (su.i & ~mi);         // v_bfi_b32
                    pr[r] = __builtin_amdgcn_exp2f(su.f);
                }
                lt += (pr[0] + pr[1]) + (pr[2] + pr[3]);
                pk[g * 2 + 0] = pkrtz(pr[0], pr[1]);
                pk[g * 2 + 1] = pkrtz(pr[2], pr[3]);
            }
            lsum += lt;

            // ---- PV for this tile: out^T += V^T . P^T (k-slots 2t, 2t+1) ----
            __builtin_amdgcn_s_setprio(1);
            #pragma unroll
            for (int kss = 0; kss < 2; ++kss) {
                const int ks = 2 * t + kss, lo4 = kss * 4;
                unsigned w0 = pk[lo4 + 0], w1 = pk[lo4 + 1];
                unsigned w2 = pk[lo4 + 2], w3 = pk[lo4 + 3];
                plswap(w0, w2);
                plswap(w1, w3);
                union { f16x8 v; unsigned u[4]; } frag;
                frag.u[0] = w0; frag.u[1] = w1;
                frag.u[2] = w2; frag.u[3] = w3;
                #pragma unroll
                for (int t2 = 0; t2 < 2; ++t2) {
                    const int vb = (t2 * 32 + q31) * 64;
                    union { f16x8 v; int4 i4; } vf;
                    vf.i4 = *(const int4*)&VT[vb + (((ks * 2 + hi) ^ swz) << 3)];
                    O[t2] = MFMA32H(vf.v, frag.v, O[t2]);
                }
            }
            __builtin_amdgcn_s_setprio(0);
        }
        lrun += lsum;
        mcur = mnext;
        kb = kb + 1; if (kb >= 3) kb -= 3;
    }

    // ---- epilogue: normalize this half, store f16 partial + denominator ----
    float l = lrun + __shfl_xor(lrun, 32);
    float inv = 1.f / l;
    _Float16* orow = (kh ? op1 : op0)
                   + (size_t)(b * N_ + q0w + q31) * 1024 + h * 64;
    #pragma unroll
    for (int t = 0; t < 2; ++t)
        #pragma unroll
        for (int g = 0; g < 4; ++g) {
            ushort4 o;
            #pragma unroll
            for (int r = 0; r < 4; ++r) {
                _Float16 hv = (_Float16)(O[t][g * 4 + r] * inv);  // RTN cvt
                ((ushort*)&o)[r] = *(ushort*)&hv;
            }
            *(ushort4*)&orow[t * 32 + g * 8 + hi * 4] = o;
        }
    if (hi == 0)
        lpart[(kh << 16) + (b * 16 + h) * 2048 + q0w + q31] = l;
}

// ---------------------------------------------------------------------------
// Combine the two key-half partials: out = (o0*l0 + o1*l1) / (l0+l1), bf16.
// attb may alias op1: each thread reads exactly the bytes it overwrites.
// ---------------------------------------------------------------------------
__global__ __launch_bounds__(256) void combine(
    const _Float16* __restrict__ op0, const _Float16* __restrict__ op1,
    const float* __restrict__ lpart, ushort* __restrict__ attb)
{
    int t = blockIdx.x * 256 + threadIdx.x;
    size_t idx = (size_t)t * 4;
    int col = (int)(idx & 1023);          // h*64 + d
    int row = (int)(idx >> 10);           // b*2048 + q
    int h = col >> 6;
    int b = row >> 11, q = row & 2047;
    int lidx = (b * 16 + h) * 2048 + q;
    float l0 = lpart[lidx], l1 = lpart[65536 + lidx];
    float inv = 1.f / (l0 + l1);
    float w0 = l0 * inv, w1 = l1 * inv;
    f16x4 a0 = *(const f16x4*)(op0 + idx);
    f16x4 a1 = *(const f16x4*)(op1 + idx);
    ushort4 o;
    #pragma unroll
    for (int r = 0; r < 4; ++r)
        ((ushort*)&o)[r] = f2bf((float)a0[r] * w0 + (float)a1[r] * w1);
    *(ushort4*)(attb + idx) = o;
}

extern "C" void kernel_launch(void* const* d_in, const int* in_sizes, int n_in,
                              void* d_out, int out_size, void* d_ws, size_t ws_size,
                              hipStream_t stream)
{
    const float* x         = (const float*)d_in[0];
    const float* ctx_ppr   = (const float*)d_in[1];
    const float* ctx_trust = (const float*)d_in[2];
    const int*   n_ctx_p   = (const int*)d_in[3];
    const int*   attn_mask = (const int*)d_in[4];
    const float* W_in      = (const float*)d_in[5];
    const float* b_in      = (const float*)d_in[6];
    const float* W_out     = (const float*)d_in[7];
    const float* b_out     = (const float*)d_in[8];
    const float* log_alpha = (const float*)d_in[9];
    const float* trust_sc  = (const float*)d_in[10];
    float* out = (float*)d_out;

    char* ws = (char*)d_ws;
    ushort*    xb       = (ushort*)ws;    ws += (size_t)4096 * 1024 * 2;   // 8 MB
    ushort*    wib      = (ushort*)ws;    ws += (size_t)3072 * 1024 * 2;   // 6 MB
    ushort*    wob      = (ushort*)ws;    ws += (size_t)1024 * 1024 * 2;   // 2 MB
    ushort*    qkb      = (ushort*)ws;    ws += (size_t)4096 * 2048 * 2;   // 16 MB
    _Float16*  vT       = (_Float16*)ws;  ws += (size_t)2048 * 2048 * 2;   // 8 MB
    ushort*    attbuf   = (ushort*)ws;    ws += (size_t)4096 * 1024 * 2;   // 8 MB
    float*     biasrow  = (float*)ws;     ws += 2048 * 4;
    unsigned*  maskbits = (unsigned*)ws;  ws += (size_t)2048 * 64 * 4;     // 512 KB

    // Split-K partials live in workspace that is dead once the QKV GEMM ran:
    //   op0   aliases xb   (8 MB, exact fit)
    //   lpart aliases wib  (512 KB into 6 MB)
    //   op1   aliases attbuf (combine reads op1[i] then writes attb[i]:
    //                         byte-identical per thread, sequential stream)
    _Float16* op0   = (_Float16*)xb;
    _Float16* op1   = (_Float16*)attbuf;
    float*    lpart = (float*)wib;

    hipLaunchKernelGGL(preprocess, dim3(8712), dim3(256), 0, stream,
                       x, W_in, W_out, ctx_ppr, log_alpha, n_ctx_p, attn_mask,
                       xb, wib, wob, biasrow, maskbits);

    hipLaunchKernelGGL((gemm_bt<128, 1>), dim3(24, 32), dim3(256), 0, stream,
                       xb, wib, b_in, (float*)nullptr, qkb, vT, TD_, 1024,
                       ctx_trust, trust_sc, n_ctx_p);

    hipLaunchKernelGGL(attn, dim3(16, 32, 2), dim3(256), 0, stream,
                       qkb, vT, maskbits, biasrow, n_ctx_p, op0, op1, lpart);

    hipLaunchKernelGGL(combine, dim3(4096), dim3(256), 0, stream,
                       op0, op1, lpart, attbuf);

    hipLaunchKernelGGL((gemm_bt<64, 0>), dim3(16, 32), dim3(256), 0, stream,
                       attbuf, wob, b_out, out, (ushort*)nullptr, (_Float16*)nullptr,
                       1024, 1024, ctx_trust, trust_sc, n_ctx_p);
}

// Round 4
// 245.939 us; speedup vs baseline: 1.0969x; 1.0084x over previous
//
#include <hip/hip_runtime.h>
#include <hip/hip_bf16.h>
#include <math.h>

#define B_   2
#define N_   2048
#define D_   1024
#define H_   16
#define TD_  3072
#define LOG2E 1.44269504088896340736f
#define SCALE_Q (0.125f * LOG2E)

typedef short  bf16x8 __attribute__((ext_vector_type(8)));
typedef _Float16 f16x8 __attribute__((ext_vector_type(8)));
typedef _Float16 f16x4 __attribute__((ext_vector_type(4)));
typedef float  f32x4  __attribute__((ext_vector_type(4)));
typedef float  f32x16 __attribute__((ext_vector_type(16)));

#define MFMA16(a, b, c)   __builtin_amdgcn_mfma_f32_16x16x32_bf16(a, b, c, 0, 0, 0)
#define MFMA32B(a, b, c)  __builtin_amdgcn_mfma_f32_32x32x16_bf16(a, b, c, 0, 0, 0)
#define MFMA32H(a, b, c)  __builtin_amdgcn_mfma_f32_32x32x16_f16(a, b, c, 0, 0, 0)

__device__ __forceinline__ ushort f2bf(float f) {
    union { float f; unsigned u; } v; v.f = f;
    unsigned r = (v.u + 0x7fffu + ((v.u >> 16) & 1u)) >> 16;
    return (ushort)r;
}
__device__ __forceinline__ unsigned pkrtz(float a, float b) {
    typedef __fp16 h2 __attribute__((ext_vector_type(2)));
    union { h2 h; unsigned u; } c;
    c.h = __builtin_amdgcn_cvt_pkrtz(a, b);
    return c.u;
}
__device__ __forceinline__ void async16(const void* g, void* l) {
    __builtin_amdgcn_global_load_lds(
        (const __attribute__((address_space(1))) unsigned*)g,
        (__attribute__((address_space(3))) unsigned*)l, 16, 0, 0);
}
// v_permlane32_swap_b32: out0 = {a.lanes[0:31], b.lanes[0:31]},
//                        out1 = {a.lanes[32:63], b.lanes[32:63]}
__device__ __forceinline__ void plswap(unsigned &a, unsigned &b) {
    auto r = __builtin_amdgcn_permlane32_swap((int)a, (int)b, false, false);
    a = (unsigned)r[0]; b = (unsigned)r[1];
}

// ---------------------------------------------------------------------------
// Preprocess: bf16 casts, mask->bitmask, log2-domain ppr bias row.
// ---------------------------------------------------------------------------
__global__ __launch_bounds__(256) void preprocess(
    const float* __restrict__ x, const float* __restrict__ W_in,
    const float* __restrict__ W_out, const float* __restrict__ ctx_ppr,
    const float* __restrict__ log_alpha, const int* __restrict__ n_ctx_p,
    const int* __restrict__ mask,
    ushort* __restrict__ xb, ushort* __restrict__ wib, ushort* __restrict__ wob,
    float* __restrict__ biasrow, unsigned* __restrict__ maskbits)
{
    const int J0 = 1048576, J1 = 786432, J2 = 262144, JM = 131072, JB = 2048;
    int t = blockIdx.x * 256 + threadIdx.x;
    if (t < J0 + J1 + J2) {
        const float* src; ushort* dst; int i = t;
        if (i < J0)           { src = x;      dst = xb;  }
        else if (i < J0 + J1) { i -= J0;      src = W_in;  dst = wib; }
        else                  { i -= J0 + J1; src = W_out; dst = wob; }
        float4 v = ((const float4*)src)[i];
        ushort4 o;
        o.x = f2bf(v.x); o.y = f2bf(v.y); o.z = f2bf(v.z); o.w = f2bf(v.w);
        ((ushort4*)dst)[i] = o;
    } else if (t < J0 + J1 + J2 + JM) {
        int i = t - (J0 + J1 + J2);
        const int4* m = (const int4*)(mask + (size_t)i * 32);
        unsigned bits = 0u;
        #pragma unroll
        for (int j = 0; j < 8; ++j) {
            int4 w = m[j];
            bits |= (w.x != 0 ? 1u : 0u) << (j * 4 + 0);
            bits |= (w.y != 0 ? 1u : 0u) << (j * 4 + 1);
            bits |= (w.z != 0 ? 1u : 0u) << (j * 4 + 2);
            bits |= (w.w != 0 ? 1u : 0u) << (j * 4 + 3);
        }
        maskbits[i] = bits;
    } else if (t < J0 + J1 + J2 + JM + JB) {
        int k = t - (J0 + J1 + J2 + JM);
        int nc = n_ctx_p[0];
        float bv = 0.f;
        if (k < nc) bv = log_alpha[0] * __log2f(fmaxf(ctx_ppr[k], 1e-8f));
        biasrow[k] = bv;   // log2-domain bias
    }
}

// ---------------------------------------------------------------------------
// bf16 MFMA NT GEMM, 128xBCOL tile, BK=64, 4 waves.
// BK=64: halves the barrier/vmcnt-drain count vs BK=32 (16 iters for K=1024)
// and doubles MFMA work per drain (32/wave). Staging uses the 64-col XOR
// pattern (slot s of row r holds col-group s^(r&7)); k accumulation order is
// identical to BK=32 (kk sub-steps walk k in sequence), so results are
// bit-identical.
// MODE 0: f32 out (+bias).  MODE 1: qkv epilogue — q*SCALE_Q->bf16 qk buffer,
// k->bf16 qk buffer, v*trust-gate->f16 V^T buffer [bh*64+dim][2048 tokens].
// ---------------------------------------------------------------------------
template<int BCOL, int MODE>
__global__ __launch_bounds__(256) void gemm_bt(
    const ushort* __restrict__ A, const ushort* __restrict__ Bw,
    const float* __restrict__ bias, float* __restrict__ Cout,
    ushort* __restrict__ qkout, _Float16* __restrict__ vTout,
    int Ncol, int K,
    const float* __restrict__ ctx_trust, const float* __restrict__ trust_scale,
    const int* __restrict__ n_ctx_p)
{
    constexpr int NT = BCOL / 32;      // col 16-tiles per wave
    __shared__ ushort tA[128 * 64];    // 16 KB
    __shared__ ushort tB[BCOL * 64];   // 16 KB (BCOL=128) / 8 KB (64)
    const int tid = threadIdx.x;
    const int lane = tid & 63, wv = tid >> 6;
    const int ln = lane & 15, kg = lane >> 4;
    const int rh = wv >> 1, ch = wv & 1;
    const int row0 = blockIdx.y * 128, col0 = blockIdx.x * BCOL;

    int offA[2][4], offB[2][NT];
    #pragma unroll
    for (int kk = 0; kk < 2; ++kk) {
        #pragma unroll
        for (int i = 0; i < 4; ++i) {
            int ra = rh * 64 + i * 16 + ln;
            offA[kk][i] = ra * 64 + (((kk * 4 + kg) ^ (ra & 7)) << 3);
        }
        #pragma unroll
        for (int i = 0; i < NT; ++i) {
            int rb = ch * (BCOL / 2) + i * 16 + ln;
            offB[kk][i] = rb * 64 + (((kk * 4 + kg) ^ (rb & 7)) << 3);
        }
    }
    f32x4 acc[4][NT];
    #pragma unroll
    for (int i = 0; i < 4; ++i)
        #pragma unroll
        for (int j = 0; j < NT; ++j) acc[i][j] = (f32x4){0.f, 0.f, 0.f, 0.f};

    for (int kt = 0; kt < K; kt += 64) {
        __syncthreads();
        #pragma unroll
        for (int r2 = 0; r2 < 4; ++r2) {               // A: 128x64
            int g = r2 * 256 + tid, row = g >> 3, sg = (g & 7) ^ (row & 7);
            async16(A + (size_t)(row0 + row) * K + kt + sg * 8, &tA[g * 8]);
        }
        #pragma unroll
        for (int r2 = 0; r2 < BCOL / 32; ++r2) {       // B: BCOLx64
            int g = r2 * 256 + tid, row = g >> 3, sg = (g & 7) ^ (row & 7);
            async16(Bw + (size_t)(col0 + row) * K + kt + sg * 8, &tB[g * 8]);
        }
        __syncthreads();
        #pragma unroll
        for (int kk = 0; kk < 2; ++kk) {
            bf16x8 af[4], bfr[NT];
            #pragma unroll
            for (int i = 0; i < 4; ++i)  af[i]  = *(const bf16x8*)&tA[offA[kk][i]];
            #pragma unroll
            for (int i = 0; i < NT; ++i) bfr[i] = *(const bf16x8*)&tB[offB[kk][i]];
            #pragma unroll
            for (int mt = 0; mt < 4; ++mt)
                #pragma unroll
                for (int nt = 0; nt < NT; ++nt)
                    acc[mt][nt] = MFMA16(af[mt], bfr[nt], acc[mt][nt]);
        }
    }

    const int nctx = n_ctx_p ? n_ctx_p[0] : 0;
    const float ts = trust_scale ? trust_scale[0] : 0.f;
    #pragma unroll
    for (int nt = 0; nt < NT; ++nt) {
        int col = col0 + ch * (BCOL / 2) + nt * 16 + ln;
        float bv = bias[col];
        #pragma unroll
        for (int mt = 0; mt < 4; ++mt) {
            int rbase = row0 + rh * 64 + mt * 16 + kg * 4;
            f32x4 a = acc[mt][nt];
            if (MODE == 0) {
                #pragma unroll
                for (int reg = 0; reg < 4; ++reg)
                    Cout[(size_t)(rbase + reg) * Ncol + col] = a[reg] + bv;
            } else {
                if (col < D_) {
                    #pragma unroll
                    for (int reg = 0; reg < 4; ++reg)
                        qkout[(size_t)(rbase + reg) * 2048 + col] =
                            f2bf((a[reg] + bv) * SCALE_Q);
                } else if (col < 2 * D_) {
                    #pragma unroll
                    for (int reg = 0; reg < 4; ++reg)
                        qkout[(size_t)(rbase + reg) * 2048 + col] = f2bf(a[reg] + bv);
                } else {
                    int vc = col - 2 * D_;
                    int hh = vc >> 6, dim = vc & 63;
                    int bb = rbase >> 11, nbase = rbase & (N_ - 1);
                    ushort4 o;
                    #pragma unroll
                    for (int reg = 0; reg < 4; ++reg) {
                        float v = a[reg] + bv;
                        int n = nbase + reg;
                        if (n < nctx) {
                            float g = 1.f / (1.f + __expf(-ts * ctx_trust[n]));
                            v *= g;
                        }
                        _Float16 hv = (_Float16)v;
                        ((ushort*)&o)[reg] = *(ushort*)&hv;
                    }
                    *(ushort4*)&vTout[((size_t)(bb * 16 + hh) * 64 + dim) * 2048 + nbase] = o;
                }
            }
        }
    }
}

// ---------------------------------------------------------------------------
// Flash attention, 32x32 MFMA, max-less log2-domain softmax.
// Split-K 2-way (blockIdx.z = key half, 16 chunks of 64 keys each).
// Counted-vmcnt pipeline: K triple-buffered (distance 2), V double-buffered
// (distance 1); raw s_barrier pairs; steady-state s_waitcnt vmcnt(7).
// VALU diet: bfe/bfi mask select, no -4 offset (constant factor cancels in
// O/l), raw v_exp_f32, p->pkrtz fused per quad. Chunk order rotated per
// block (softmax sum is commutative) so co-resident blocks de-convoy their
// VALU/MFMA phases; s_setprio(1) around MFMA clusters.
// ---------------------------------------------------------------------------
__global__ __launch_bounds__(256, 4) void attn(
    const ushort* __restrict__ qkb,      // [4096][2048] bf16: q | k
    const _Float16* __restrict__ vT,     // [32*64][2048] f16  (b,h,dim) x token
    const unsigned* __restrict__ maskbits,
    const float* __restrict__ biasrow,   // log2-domain, 0 beyond n_ctx
    const int* __restrict__ n_ctx_p,
    _Float16* __restrict__ op0,          // [4096][1024] f16 partial, key-half 0
    _Float16* __restrict__ op1,          // [4096][1024] f16 partial, key-half 1
    float* __restrict__ lpart)           // [2][32*2048] denominators
{
    __shared__ ushort   Kt[3][64 * 64];  // 24 KB
    __shared__ _Float16 Vt[2][64 * 64];  // 16 KB
    const int tid = threadIdx.x;
    const int lane = tid & 63, wv = tid >> 6;
    const int q31 = lane & 31, hi = lane >> 5;
    const int b = blockIdx.y >> 4, h = blockIdx.y & 15;
    const int q0w = blockIdx.x * 128 + wv * 32;
    const int kh = blockIdx.z;           // key half: 0 or 1
    const int kbase = kh << 10;
    const int nctx = n_ctx_p[0];

    // chunk-order rotation: co-resident blocks are ~256 apart in linear id
    const int lin = blockIdx.x + (blockIdx.y << 4) + (blockIdx.z << 9);
    const int rot = ((lin >> 8) << 2) & 15;

    union fi { float f; int i; };
    fi ng; ng.f = -1e30f;
    const int NEGI = ng.i;

    // Q B-fragments: B[k=dim][n=q], lane n=q31, k = hi*8+j per kstep
    bf16x8 qf[4];
    {
        const ushort* qrow = qkb + (size_t)(b * N_ + q0w + q31) * 2048 + h * 64;
        #pragma unroll
        for (int ks = 0; ks < 4; ++ks)
            qf[ks] = *(const bf16x8*)(qrow + ks * 16 + hi * 8);
    }
    const size_t kgbase = (size_t)(b * N_ + kbase) * 2048 + 1024 + h * 64;
    const _Float16* vbase = vT + (size_t)((b * 16 + h) * 64) * 2048 + kbase;
    const unsigned* mrow = maskbits + (size_t)(q0w + q31) * 64 + (kbase >> 5);

    // per-thread staging offsets within one 64x64 chunk (2B elements):
    // slot r2: g = r2*256+tid, row = g>>3, col-group sg = (g&7)^(row&7)
    int goff[2], ldso[2];
    #pragma unroll
    for (int r2 = 0; r2 < 2; ++r2) {
        int g = r2 * 256 + tid, row = g >> 3, sg = (g & 7) ^ (row & 7);
        goff[r2] = row * 2048 + sg * 8;
        ldso[r2] = g * 8;
    }

    f32x16 O[2];
    O[0] = (f32x16)(0.f); O[1] = (f32x16)(0.f);
    float lrun = 0.f;

    // ---- prologue: FIFO = [mask0][K0 x2][V0 x2][K1 x2] (rotated chunks) ----
    const int cp0 = rot, cp1 = (rot + 1) & 15;
    uint2 mcur = *(const uint2*)&mrow[cp0 * 2];
    asm volatile("" ::: "memory");       // pin mask load before the asyncs
    {
        const ushort* gp0 = qkb + kgbase + (size_t)cp0 * (64 * 2048);
        #pragma unroll
        for (int r2 = 0; r2 < 2; ++r2) async16(gp0 + goff[r2], &Kt[0][ldso[r2]]);
        const _Float16* vp = vbase + cp0 * 64;
        #pragma unroll
        for (int r2 = 0; r2 < 2; ++r2) async16(vp + goff[r2], &Vt[0][ldso[r2]]);
        const ushort* gp1 = qkb + kgbase + (size_t)cp1 * (64 * 2048);
        #pragma unroll
        for (int r2 = 0; r2 < 2; ++r2) async16(gp1 + goff[r2], &Kt[1][ldso[r2]]);
    }

    const int swz = q31 & 7;
    int kb = 0;                           // Kt buffer holding chunk ci
    #pragma unroll 1
    for (int ci = 0; ci < 16; ++ci) {
        // bar1: all waves done computing chunk ci-1 -> buffers reusable
        asm volatile("s_barrier" ::: "memory");
        uint2 mnext = mcur;
        if (ci < 15) {
            const int cpv = (ci + 1 + rot) & 15;
            mnext = *(const uint2*)&mrow[cpv * 2];
            asm volatile("" ::: "memory");   // pin mask before V asyncs
            const _Float16* vp = vbase + cpv * 64;
            #pragma unroll
            for (int r2 = 0; r2 < 2; ++r2)
                async16(vp + goff[r2], &Vt[(ci + 1) & 1][ldso[r2]]);
        }
        if (ci < 14) {
            int nb = kb + 2; if (nb >= 3) nb -= 3;
            const int cpk = (ci + 2 + rot) & 15;
            const ushort* gp = qkb + kgbase + (size_t)cpk * (64 * 2048);
            #pragma unroll
            for (int r2 = 0; r2 < 2; ++r2)
                async16(gp + goff[r2], &Kt[nb][ldso[r2]]);
        }
        // counted wait: retire through V(ci)+mask(ci); keep newer prefetches
        // in flight. Steady: [Kci+1 x2][maskci+1][Vci+1 x2][Kci+2 x2] = 7.
        if (ci < 14)       asm volatile("s_waitcnt vmcnt(7)" ::: "memory");
        else if (ci == 14) asm volatile("s_waitcnt vmcnt(5)" ::: "memory");
        else               asm volatile("s_waitcnt vmcnt(0)" ::: "memory");
        // bar2: all waves' chunk-ci loads have landed
        asm volatile("s_barrier" ::: "memory");

        const ushort*   KT = Kt[kb];
        const _Float16* VT = Vt[ci & 1];
        const int cp = (ci + rot) & 15;
        const int c0g = kbase + cp * 64;
        const bool has_bias = (c0g < nctx);
        float lsum = 0.f;

        #pragma unroll
        for (int t = 0; t < 2; ++t) {
            // ---- S^T tile = K . Q^T ----
            f32x16 S = (f32x16)(0.f);
            const int rbase = (t * 32 + q31) * 64;
            __builtin_amdgcn_s_setprio(1);
            #pragma unroll
            for (int ks = 0; ks < 4; ++ks) {
                bf16x8 kf = *(const bf16x8*)&KT[rbase + (((ks * 2 + hi) ^ swz) << 3)];
                S = MFMA32B(kf, qf[ks], S);
            }
            __builtin_amdgcn_s_setprio(0);

            // ---- softmax (no max, no offset; mask via bfe+bfi) ----
            const unsigned msh = (t ? mcur.y : mcur.x) >> (hi * 4);
            unsigned pk[8];
            float lt = 0.f;
            #pragma unroll
            for (int g = 0; g < 4; ++g) {
                f32x4 bb;
                if (has_bias)
                    bb = *(const f32x4*)&biasrow[c0g + t * 32 + g * 8 + hi * 4];
                float pr[4];
                #pragma unroll
                for (int r = 0; r < 4; ++r) {
                    const int br = r + 8 * g;      // bit pos after >> 4*hi
                    float s = S[g * 4 + r];
                    if (has_bias) s += bb[r];
                    int mi = ((int)(msh << (31 - br))) >> 31;  // v_bfe_i32
                    fi su; su.f = s;
                    su.i = (mi & NEGI) | (su.i & ~mi);         // v_bfi_b32
                    pr[r] = __builtin_amdgcn_exp2f(su.f);
                }
                lt += (pr[0] + pr[1]) + (pr[2] + pr[3]);
                pk[g * 2 + 0] = pkrtz(pr[0], pr[1]);
                pk[g * 2 + 1] = pkrtz(pr[2], pr[3]);
            }
            lsum += lt;

            // ---- PV for this tile: out^T += V^T . P^T (k-slots 2t, 2t+1) ----
            __builtin_amdgcn_s_setprio(1);
            #pragma unroll
            for (int kss = 0; kss < 2; ++kss) {
                const int ks = 2 * t + kss, lo4 = kss * 4;
                unsigned w0 = pk[lo4 + 0], w1 = pk[lo4 + 1];
                unsigned w2 = pk[lo4 + 2], w3 = pk[lo4 + 3];
                plswap(w0, w2);
                plswap(w1, w3);
                union { f16x8 v; unsigned u[4]; } frag;
                frag.u[0] = w0; frag.u[1] = w1;
                frag.u[2] = w2; frag.u[3] = w3;
                #pragma unroll
                for (int t2 = 0; t2 < 2; ++t2) {
                    const int vb = (t2 * 32 + q31) * 64;
                    union { f16x8 v; int4 i4; } vf;
                    vf.i4 = *(const int4*)&VT[vb + (((ks * 2 + hi) ^ swz) << 3)];
                    O[t2] = MFMA32H(vf.v, frag.v, O[t2]);
                }
            }
            __builtin_amdgcn_s_setprio(0);
        }
        lrun += lsum;
        mcur = mnext;
        kb = kb + 1; if (kb >= 3) kb -= 3;
    }

    // ---- epilogue: normalize this half, store f16 partial + denominator ----
    float l = lrun + __shfl_xor(lrun, 32);
    float inv = 1.f / l;
    _Float16* orow = (kh ? op1 : op0)
                   + (size_t)(b * N_ + q0w + q31) * 1024 + h * 64;
    #pragma unroll
    for (int t = 0; t < 2; ++t)
        #pragma unroll
        for (int g = 0; g < 4; ++g) {
            ushort4 o;
            #pragma unroll
            for (int r = 0; r < 4; ++r) {
                _Float16 hv = (_Float16)(O[t][g * 4 + r] * inv);  // RTN cvt
                ((ushort*)&o)[r] = *(ushort*)&hv;
            }
            *(ushort4*)&orow[t * 32 + g * 8 + hi * 4] = o;
        }
    if (hi == 0)
        lpart[(kh << 16) + (b * 16 + h) * 2048 + q0w + q31] = l;
}

// ---------------------------------------------------------------------------
// Combine the two key-half partials: out = (o0*l0 + o1*l1) / (l0+l1), bf16.
// attb may alias op1: each thread reads exactly the bytes it overwrites.
// ---------------------------------------------------------------------------
__global__ __launch_bounds__(256) void combine(
    const _Float16* __restrict__ op0, const _Float16* __restrict__ op1,
    const float* __restrict__ lpart, ushort* __restrict__ attb)
{
    int t = blockIdx.x * 256 + threadIdx.x;
    size_t idx = (size_t)t * 4;
    int col = (int)(idx & 1023);          // h*64 + d
    int row = (int)(idx >> 10);           // b*2048 + q
    int h = col >> 6;
    int b = row >> 11, q = row & 2047;
    int lidx = (b * 16 + h) * 2048 + q;
    float l0 = lpart[lidx], l1 = lpart[65536 + lidx];
    float inv = 1.f / (l0 + l1);
    float w0 = l0 * inv, w1 = l1 * inv;
    f16x4 a0 = *(const f16x4*)(op0 + idx);
    f16x4 a1 = *(const f16x4*)(op1 + idx);
    ushort4 o;
    #pragma unroll
    for (int r = 0; r < 4; ++r)
        ((ushort*)&o)[r] = f2bf((float)a0[r] * w0 + (float)a1[r] * w1);
    *(ushort4*)(attb + idx) = o;
}

extern "C" void kernel_launch(void* const* d_in, const int* in_sizes, int n_in,
                              void* d_out, int out_size, void* d_ws, size_t ws_size,
                              hipStream_t stream)
{
    const float* x         = (const float*)d_in[0];
    const float* ctx_ppr   = (const float*)d_in[1];
    const float* ctx_trust = (const float*)d_in[2];
    const int*   n_ctx_p   = (const int*)d_in[3];
    const int*   attn_mask = (const int*)d_in[4];
    const float* W_in      = (const float*)d_in[5];
    const float* b_in      = (const float*)d_in[6];
    const float* W_out     = (const float*)d_in[7];
    const float* b_out     = (const float*)d_in[8];
    const float* log_alpha = (const float*)d_in[9];
    const float* trust_sc  = (const float*)d_in[10];
    float* out = (float*)d_out;

    char* ws = (char*)d_ws;
    ushort*    xb       = (ushort*)ws;    ws += (size_t)4096 * 1024 * 2;   // 8 MB
    ushort*    wib      = (ushort*)ws;    ws += (size_t)3072 * 1024 * 2;   // 6 MB
    ushort*    wob      = (ushort*)ws;    ws += (size_t)1024 * 1024 * 2;   // 2 MB
    ushort*    qkb      = (ushort*)ws;    ws += (size_t)4096 * 2048 * 2;   // 16 MB
    _Float16*  vT       = (_Float16*)ws;  ws += (size_t)2048 * 2048 * 2;   // 8 MB
    ushort*    attbuf   = (ushort*)ws;    ws += (size_t)4096 * 1024 * 2;   // 8 MB
    float*     biasrow  = (float*)ws;     ws += 2048 * 4;
    unsigned*  maskbits = (unsigned*)ws;  ws += (size_t)2048 * 64 * 4;     // 512 KB

    // Split-K partials live in workspace that is dead once the QKV GEMM ran:
    //   op0   aliases xb   (8 MB, exact fit)
    //   lpart aliases wib  (512 KB into 6 MB)
    //   op1   aliases attbuf (combine reads op1[i] then writes attb[i]:
    //                         byte-identical per thread, sequential stream)
    _Float16* op0   = (_Float16*)xb;
    _Float16* op1   = (_Float16*)attbuf;
    float*    lpart = (float*)wib;

    hipLaunchKernelGGL(preprocess, dim3(8712), dim3(256), 0, stream,
                       x, W_in, W_out, ctx_ppr, log_alpha, n_ctx_p, attn_mask,
                       xb, wib, wob, biasrow, maskbits);

    hipLaunchKernelGGL((gemm_bt<128, 1>), dim3(24, 32), dim3(256), 0, stream,
                       xb, wib, b_in, (float*)nullptr, qkb, vT, TD_, 1024,
                       ctx_trust, trust_sc, n_ctx_p);

    hipLaunchKernelGGL(attn, dim3(16, 32, 2), dim3(256), 0, stream,
                       qkb, vT, maskbits, biasrow, n_ctx_p, op0, op1, lpart);

    hipLaunchKernelGGL(combine, dim3(4096), dim3(256), 0, stream,
                       op0, op1, lpart, attbuf);

    hipLaunchKernelGGL((gemm_bt<64, 0>), dim3(16, 32), dim3(256), 0, stream,
                       attbuf, wob, b_out, out, (ushort*)nullptr, (_Float16*)nullptr,
                       1024, 1024, ctx_trust, trust_sc, n_ctx_p);
}